// Round 1
// baseline (1068.384 us; speedup 1.0000x reference)
//
#include <hip/hip_runtime.h>
#include <hip/hip_bf16.h>

// Problem: out[M=4096][N=16384] = x[M][K=4096] @ (W[N][K] * scale[N/128][K/128])^T + bias[N]
#define M_DIM 4096
#define N_DIM 16384
#define K_DIM 4096

typedef __bf16 bf16x8 __attribute__((ext_vector_type(8)));
typedef float f32x4 __attribute__((ext_vector_type(4)));

__device__ __forceinline__ void gload16(const void* g, void* l) {
    __builtin_amdgcn_global_load_lds((__attribute__((address_space(1))) void*)g,
                                     (__attribute__((address_space(3))) void*)l, 16, 0, 0);
}

// ---------- prepass 1: x fp32 -> bf16 ----------
__global__ __launch_bounds__(256) void cvt_x_kernel(const float* __restrict__ x,
                                                    __hip_bfloat16* __restrict__ out,
                                                    int ngroups) {
    int i = blockIdx.x * blockDim.x + threadIdx.x;
    int stride = gridDim.x * blockDim.x;
    for (; i < ngroups; i += stride) {
        const float4* p = (const float4*)(x + (size_t)i * 8);
        float4 v0 = p[0];
        float4 v1 = p[1];
        bf16x8 r;
        r[0] = (__bf16)v0.x; r[1] = (__bf16)v0.y; r[2] = (__bf16)v0.z; r[3] = (__bf16)v0.w;
        r[4] = (__bf16)v1.x; r[5] = (__bf16)v1.y; r[6] = (__bf16)v1.z; r[7] = (__bf16)v1.w;
        *(bf16x8*)(out + (size_t)i * 8) = r;
    }
}

// ---------- prepass 2: W fp32 * blockscale -> bf16 ----------
__global__ __launch_bounds__(256) void dequant_w_kernel(const float* __restrict__ w,
                                                        const float* __restrict__ scale,
                                                        __hip_bfloat16* __restrict__ out) {
    const int ngroups = N_DIM * (K_DIM / 8);   // groups of 8 along K
    int i = blockIdx.x * blockDim.x + threadIdx.x;
    int stride = gridDim.x * blockDim.x;
    for (; i < ngroups; i += stride) {
        int row = i >> 9;            // K/8 = 512 groups per row
        int cg  = i & 511;           // col-group; col = cg*8
        float s = scale[(row >> 7) * (K_DIM / 128) + (cg >> 4)];
        const float4* p = (const float4*)(w + (size_t)i * 8);
        float4 v0 = p[0];
        float4 v1 = p[1];
        bf16x8 r;
        r[0] = (__bf16)(v0.x * s); r[1] = (__bf16)(v0.y * s);
        r[2] = (__bf16)(v0.z * s); r[3] = (__bf16)(v0.w * s);
        r[4] = (__bf16)(v1.x * s); r[5] = (__bf16)(v1.y * s);
        r[6] = (__bf16)(v1.z * s); r[7] = (__bf16)(v1.w * s);
        *(bf16x8*)(out + (size_t)i * 8) = r;
    }
}

// ---------- main GEMM: m97-structure 128x128 tile, BK=64, 4 waves ----------
__global__ __launch_bounds__(256)
void gemm_bf16_kernel(const __hip_bfloat16* __restrict__ A,   // [M][K] bf16
                      const __hip_bfloat16* __restrict__ Bw,  // [N][K] bf16
                      const float* __restrict__ bias,
                      float* __restrict__ C) {                // [M][N] fp32
    constexpr int Mtiles = M_DIM / 128;            // 32
    constexpr int Ntiles = N_DIM / 128;            // 128
    constexpr int nwg = Mtiles * Ntiles;           // 4096 (divisible by 8)
    int bid = blockIdx.x;
    // XCD-aware bijective swizzle (nwg % 8 == 0)
    int swz = (bid & 7) * (nwg >> 3) + (bid >> 3);
    int bm = swz % Mtiles;
    int bn = swz / Mtiles;

    __shared__ __align__(16) __hip_bfloat16 sA[128 * 64];   // 16 KiB
    __shared__ __align__(16) __hip_bfloat16 sB[128 * 64];   // 16 KiB

    const int t = threadIdx.x;
    const int l = t & 63;
    const int w = t >> 6;      // wave 0..3
    const int wm = w & 1;      // wave row (2 in M)
    const int wn = w >> 1;     // wave col (2 in N)

    const int lr = l & 15;     // fragment row/col
    const int lk = l >> 4;     // k-group 0..3 -> k offset lk*8

    f32x4 acc[4][4] = {};

    const size_t K = K_DIM;
    const __hip_bfloat16* aBase = A  + (size_t)(bm * 128) * K;
    const __hip_bfloat16* bBase = Bw + (size_t)(bn * 128) * K;

    for (int kt = 0; kt < K_DIM / 64; ++kt) {
        const __hip_bfloat16* a0 = aBase + kt * 64;
        const __hip_bfloat16* b0 = bBase + kt * 64;
        // stage 128x64 bf16 (16 KiB each). Linear LDS layout; per-lane global addr.
        // byte off = i*4096 + w*1024 + l*16 ; row = off/128 ; colbyte = off%128
        #pragma unroll
        for (int i = 0; i < 4; ++i) {
            int off  = i * 4096 + w * 1024 + l * 16;
            int row  = off >> 7;
            int cole = (off & 127) >> 1;   // element offset in row
            gload16(a0 + (size_t)row * K + cole, (char*)sA + i * 4096 + w * 1024);
            gload16(b0 + (size_t)row * K + cole, (char*)sB + i * 4096 + w * 1024);
        }
        __syncthreads();   // drains vmcnt(0) before barrier (compiler-inserted)

        #pragma unroll
        for (int kk = 0; kk < 2; ++kk) {
            bf16x8 af[4], bfr[4];
            #pragma unroll
            for (int mi = 0; mi < 4; ++mi) {
                int row = wm * 64 + mi * 16 + lr;
                af[mi] = *(const bf16x8*)(sA + row * 64 + kk * 32 + lk * 8);
            }
            #pragma unroll
            for (int ni = 0; ni < 4; ++ni) {
                int row = wn * 64 + ni * 16 + lr;
                bfr[ni] = *(const bf16x8*)(sB + row * 64 + kk * 32 + lk * 8);
            }
            #pragma unroll
            for (int mi = 0; mi < 4; ++mi)
                #pragma unroll
                for (int ni = 0; ni < 4; ++ni)
                    acc[mi][ni] = __builtin_amdgcn_mfma_f32_16x16x32_bf16(
                        af[mi], bfr[ni], acc[mi][ni], 0, 0, 0);
        }
        __syncthreads();
    }

    // epilogue: C/D layout col=lane&15, row=(lane>>4)*4+reg  [m89-verified]
    const int crow0 = bm * 128 + wm * 64;
    const int ccol0 = bn * 128 + wn * 64;
    #pragma unroll
    for (int ni = 0; ni < 4; ++ni) {
        int col = ccol0 + ni * 16 + lr;
        float bv = bias[col];
        #pragma unroll
        for (int mi = 0; mi < 4; ++mi) {
            int rbase = crow0 + mi * 16 + lk * 4;
            #pragma unroll
            for (int j = 0; j < 4; ++j) {
                C[(size_t)(rbase + j) * N_DIM + col] = acc[mi][ni][j] + bv;
            }
        }
    }
}

// ---------- fallback (ws too small): fp32 LDS-tiled, correct but slow ----------
__global__ __launch_bounds__(256)
void gemm_fallback(const float* __restrict__ X, const float* __restrict__ W,
                   const float* __restrict__ scale, const float* __restrict__ bias,
                   float* __restrict__ C) {
    int bm = blockIdx.x % (M_DIM / 64);
    int bn = blockIdx.x / (M_DIM / 64);
    __shared__ float sA[64][33];
    __shared__ float sB[64][33];
    int t = threadIdx.x;
    int tx = t & 15, ty = t >> 4;
    float acc[4][4] = {};
    for (int kt = 0; kt < K_DIM / 32; ++kt) {
        float s = scale[(bn >> 1) * (K_DIM / 128) + (kt >> 2)];
        #pragma unroll
        for (int i = 0; i < 8; ++i) {
            int idx = t + i * 256;
            int r = idx >> 5, c = idx & 31;
            sA[r][c] = X[(size_t)(bm * 64 + r) * K_DIM + kt * 32 + c];
            sB[r][c] = W[(size_t)(bn * 64 + r) * K_DIM + kt * 32 + c] * s;
        }
        __syncthreads();
        #pragma unroll
        for (int k = 0; k < 32; ++k) {
            float a[4], b[4];
            #pragma unroll
            for (int i = 0; i < 4; ++i) a[i] = sA[ty * 4 + i][k];
            #pragma unroll
            for (int j = 0; j < 4; ++j) b[j] = sB[tx * 4 + j][k];
            #pragma unroll
            for (int i = 0; i < 4; ++i)
                #pragma unroll
                for (int j = 0; j < 4; ++j) acc[i][j] += a[i] * b[j];
        }
        __syncthreads();
    }
    #pragma unroll
    for (int i = 0; i < 4; ++i)
        #pragma unroll
        for (int j = 0; j < 4; ++j) {
            int row = bm * 64 + ty * 4 + i;
            int col = bn * 64 + tx * 4 + j;
            C[(size_t)row * N_DIM + col] = acc[i][j] + bias[col];
        }
}

extern "C" void kernel_launch(void* const* d_in, const int* in_sizes, int n_in,
                              void* d_out, int out_size, void* d_ws, size_t ws_size,
                              hipStream_t stream) {
    const float* x     = (const float*)d_in[0];   // [2,2048,4096]
    const float* wgt   = (const float*)d_in[1];   // [16384,4096]
    const float* scale = (const float*)d_in[2];   // [128,32]
    const float* bias  = (const float*)d_in[3];   // [16384]
    float* out = (float*)d_out;                   // [2,2048,16384]

    const size_t need = ((size_t)M_DIM * K_DIM + (size_t)N_DIM * K_DIM) * sizeof(__hip_bfloat16);
    if (ws_size >= need) {
        __hip_bfloat16* xbf = (__hip_bfloat16*)d_ws;
        __hip_bfloat16* wbf = xbf + (size_t)M_DIM * K_DIM;
        cvt_x_kernel<<<2048, 256, 0, stream>>>(x, xbf, M_DIM * K_DIM / 8);
        dequant_w_kernel<<<4096, 256, 0, stream>>>(wgt, scale, wbf);
        gemm_bf16_kernel<<<(M_DIM / 128) * (N_DIM / 128), 256, 0, stream>>>(xbf, wbf, bias, out);
    } else {
        gemm_fallback<<<(M_DIM / 64) * (N_DIM / 64), 256, 0, stream>>>(x, wgt, scale, bias, out);
    }
}

// Round 2
// 1037.727 us; speedup vs baseline: 1.0295x; 1.0295x over previous
//
#include <hip/hip_runtime.h>
#include <hip/hip_bf16.h>

// Problem: out[M=4096][N=16384] = x[M][K=4096] @ (W[N][K] * scale[N/128][K/128])^T + bias[N]
#define M_DIM 4096
#define N_DIM 16384
#define K_DIM 4096

typedef __bf16 bf16x8 __attribute__((ext_vector_type(8)));
typedef float f32x4 __attribute__((ext_vector_type(4)));

__device__ __forceinline__ void gload16(const void* g, void* l) {
    __builtin_amdgcn_global_load_lds((__attribute__((address_space(1))) void*)g,
                                     (__attribute__((address_space(3))) void*)l, 16, 0, 0);
}

// ---------- prepass 1: x fp32 -> bf16 ----------
__global__ __launch_bounds__(256) void cvt_x_kernel(const float* __restrict__ x,
                                                    __hip_bfloat16* __restrict__ out,
                                                    int ngroups) {
    int i = blockIdx.x * blockDim.x + threadIdx.x;
    int stride = gridDim.x * blockDim.x;
    for (; i < ngroups; i += stride) {
        const float4* p = (const float4*)(x + (size_t)i * 8);
        float4 v0 = p[0];
        float4 v1 = p[1];
        bf16x8 r;
        r[0] = (__bf16)v0.x; r[1] = (__bf16)v0.y; r[2] = (__bf16)v0.z; r[3] = (__bf16)v0.w;
        r[4] = (__bf16)v1.x; r[5] = (__bf16)v1.y; r[6] = (__bf16)v1.z; r[7] = (__bf16)v1.w;
        *(bf16x8*)(out + (size_t)i * 8) = r;
    }
}

// ---------- prepass 2: W fp32 * blockscale -> bf16 ----------
__global__ __launch_bounds__(256) void dequant_w_kernel(const float* __restrict__ w,
                                                        const float* __restrict__ scale,
                                                        __hip_bfloat16* __restrict__ out) {
    const int ngroups = N_DIM * (K_DIM / 8);   // groups of 8 along K
    int i = blockIdx.x * blockDim.x + threadIdx.x;
    int stride = gridDim.x * blockDim.x;
    for (; i < ngroups; i += stride) {
        int row = i >> 9;            // K/8 = 512 groups per row
        int cg  = i & 511;           // col-group; col = cg*8
        float s = scale[(row >> 7) * (K_DIM / 128) + (cg >> 4)];
        const float4* p = (const float4*)(w + (size_t)i * 8);
        float4 v0 = p[0];
        float4 v1 = p[1];
        bf16x8 r;
        r[0] = (__bf16)(v0.x * s); r[1] = (__bf16)(v0.y * s);
        r[2] = (__bf16)(v0.z * s); r[3] = (__bf16)(v0.w * s);
        r[4] = (__bf16)(v1.x * s); r[5] = (__bf16)(v1.y * s);
        r[6] = (__bf16)(v1.z * s); r[7] = (__bf16)(v1.w * s);
        *(bf16x8*)(out + (size_t)i * 8) = r;
    }
}

// ---------- main GEMM: m97-structure 128x128 tile, BK=64, 4 waves ----------
// T2 fix vs round 1: XOR-swizzle the LDS tiles (byte ^= (row&7)<<4) to kill the
// 16-way bank conflict on ds_read_b128. Rule #21: global_load_lds writes
// linearly, so the swizzle is applied by PRE-SWIZZLING the per-lane GLOBAL
// source address (same involution), LDS dest stays linear; reads apply the
// same XOR. Within each 8-lane group the 8 rows now map to 8 distinct 16-B
// slots -> all 32 banks covered, and group still reads one 128-B row segment
// from global (coalescing preserved).
__global__ __launch_bounds__(256)
void gemm_bf16_kernel(const __hip_bfloat16* __restrict__ A,   // [M][K] bf16
                      const __hip_bfloat16* __restrict__ Bw,  // [N][K] bf16
                      const float* __restrict__ bias,
                      float* __restrict__ C) {                // [M][N] fp32
    constexpr int Mtiles = M_DIM / 128;            // 32
    constexpr int Ntiles = N_DIM / 128;            // 128
    constexpr int nwg = Mtiles * Ntiles;           // 4096 (divisible by 8)
    int bid = blockIdx.x;
    // XCD-aware bijective swizzle (nwg % 8 == 0)
    int swz = (bid & 7) * (nwg >> 3) + (bid >> 3);
    int bm = swz % Mtiles;
    int bn = swz / Mtiles;

    __shared__ __align__(16) __hip_bfloat16 sA[128 * 64];   // 16 KiB
    __shared__ __align__(16) __hip_bfloat16 sB[128 * 64];   // 16 KiB

    const int t = threadIdx.x;
    const int l = t & 63;
    const int w = t >> 6;      // wave 0..3
    const int wm = w & 1;      // wave row (2 in M)
    const int wn = w >> 1;     // wave col (2 in N)

    const int lr = l & 15;     // fragment row/col
    const int lk = l >> 4;     // k-group 0..3 -> k offset lk*8
    const int rxor = (lr & 7) << 3;  // element-XOR term for fragment reads

    // staging: lane l of wave w, chunk i writes LDS bytes [i*4096+w*1024+l*16, +16)
    // linear dest -> stored row r = i*32 + w*8 + (l>>3); stored byte-col (l&7)*16.
    // pre-swizzled global col so that LDS[r][c] holds logical (r, c ^ ((r&7)<<4)):
    const int srow_lo = l >> 3;                        // r & 7 contribution
    const int scol_e  = ((l & 7) ^ srow_lo) << 3;      // element col in row (0..56)

    f32x4 acc[4][4] = {};

    const size_t K = K_DIM;
    const __hip_bfloat16* aBase = A  + (size_t)(bm * 128) * K;
    const __hip_bfloat16* bBase = Bw + (size_t)(bn * 128) * K;

    for (int kt = 0; kt < K_DIM / 64; ++kt) {
        const __hip_bfloat16* a0 = aBase + kt * 64;
        const __hip_bfloat16* b0 = bBase + kt * 64;
        #pragma unroll
        for (int i = 0; i < 4; ++i) {
            int r = i * 32 + w * 8 + srow_lo;
            gload16(a0 + (size_t)r * K + scol_e, (char*)sA + i * 4096 + w * 1024);
            gload16(b0 + (size_t)r * K + scol_e, (char*)sB + i * 4096 + w * 1024);
        }
        __syncthreads();

        #pragma unroll
        for (int kk = 0; kk < 2; ++kk) {
            bf16x8 af[4], bfr[4];
            const int csw = (kk * 32 + lk * 8) ^ rxor;   // swizzled element col
            #pragma unroll
            for (int mi = 0; mi < 4; ++mi) {
                int row = wm * 64 + mi * 16 + lr;
                af[mi] = *(const bf16x8*)(sA + row * 64 + csw);
            }
            #pragma unroll
            for (int ni = 0; ni < 4; ++ni) {
                int row = wn * 64 + ni * 16 + lr;
                bfr[ni] = *(const bf16x8*)(sB + row * 64 + csw);
            }
            #pragma unroll
            for (int mi = 0; mi < 4; ++mi)
                #pragma unroll
                for (int ni = 0; ni < 4; ++ni)
                    acc[mi][ni] = __builtin_amdgcn_mfma_f32_16x16x32_bf16(
                        af[mi], bfr[ni], acc[mi][ni], 0, 0, 0);
        }
        __syncthreads();
    }

    // epilogue: C/D layout col=lane&15, row=(lane>>4)*4+reg  [m89-verified]
    const int crow0 = bm * 128 + wm * 64;
    const int ccol0 = bn * 128 + wn * 64;
    #pragma unroll
    for (int ni = 0; ni < 4; ++ni) {
        int col = ccol0 + ni * 16 + lr;
        float bv = bias[col];
        #pragma unroll
        for (int mi = 0; mi < 4; ++mi) {
            int rbase = crow0 + mi * 16 + lk * 4;
            #pragma unroll
            for (int j = 0; j < 4; ++j) {
                C[(size_t)(rbase + j) * N_DIM + col] = acc[mi][ni][j] + bv;
            }
        }
    }
}

// ---------- fallback (ws too small): fp32 LDS-tiled, correct but slow ----------
__global__ __launch_bounds__(256)
void gemm_fallback(const float* __restrict__ X, const float* __restrict__ W,
                   const float* __restrict__ scale, const float* __restrict__ bias,
                   float* __restrict__ C) {
    int bm = blockIdx.x % (M_DIM / 64);
    int bn = blockIdx.x / (M_DIM / 64);
    __shared__ float sA[64][33];
    __shared__ float sB[64][33];
    int t = threadIdx.x;
    int tx = t & 15, ty = t >> 4;
    float acc[4][4] = {};
    for (int kt = 0; kt < K_DIM / 32; ++kt) {
        float s = scale[(bn >> 1) * (K_DIM / 128) + (kt >> 2)];
        #pragma unroll
        for (int i = 0; i < 8; ++i) {
            int idx = t + i * 256;
            int r = idx >> 5, c = idx & 31;
            sA[r][c] = X[(size_t)(bm * 64 + r) * K_DIM + kt * 32 + c];
            sB[r][c] = W[(size_t)(bn * 64 + r) * K_DIM + kt * 32 + c] * s;
        }
        __syncthreads();
        #pragma unroll
        for (int k = 0; k < 32; ++k) {
            float a[4], b[4];
            #pragma unroll
            for (int i = 0; i < 4; ++i) a[i] = sA[ty * 4 + i][k];
            #pragma unroll
            for (int j = 0; j < 4; ++j) b[j] = sB[tx * 4 + j][k];
            #pragma unroll
            for (int i = 0; i < 4; ++i)
                #pragma unroll
                for (int j = 0; j < 4; ++j) acc[i][j] += a[i] * b[j];
        }
        __syncthreads();
    }
    #pragma unroll
    for (int i = 0; i < 4; ++i)
        #pragma unroll
        for (int j = 0; j < 4; ++j) {
            int row = bm * 64 + ty * 4 + i;
            int col = bn * 64 + tx * 4 + j;
            C[(size_t)row * N_DIM + col] = acc[i][j] + bias[col];
        }
}

extern "C" void kernel_launch(void* const* d_in, const int* in_sizes, int n_in,
                              void* d_out, int out_size, void* d_ws, size_t ws_size,
                              hipStream_t stream) {
    const float* x     = (const float*)d_in[0];   // [2,2048,4096]
    const float* wgt   = (const float*)d_in[1];   // [16384,4096]
    const float* scale = (const float*)d_in[2];   // [128,32]
    const float* bias  = (const float*)d_in[3];   // [16384]
    float* out = (float*)d_out;                   // [2,2048,16384]

    const size_t need = ((size_t)M_DIM * K_DIM + (size_t)N_DIM * K_DIM) * sizeof(__hip_bfloat16);
    if (ws_size >= need) {
        __hip_bfloat16* xbf = (__hip_bfloat16*)d_ws;
        __hip_bfloat16* wbf = xbf + (size_t)M_DIM * K_DIM;
        cvt_x_kernel<<<2048, 256, 0, stream>>>(x, xbf, M_DIM * K_DIM / 8);
        dequant_w_kernel<<<4096, 256, 0, stream>>>(wgt, scale, wbf);
        gemm_bf16_kernel<<<(M_DIM / 128) * (N_DIM / 128), 256, 0, stream>>>(xbf, wbf, bias, out);
    } else {
        gemm_fallback<<<(M_DIM / 64) * (N_DIM / 64), 256, 0, stream>>>(x, wgt, scale, bias, out);
    }
}

// Round 3
// 777.554 us; speedup vs baseline: 1.3740x; 1.3346x over previous
//
#include <hip/hip_runtime.h>
#include <hip/hip_bf16.h>

// Problem: out[M=4096][N=16384] = x[M][K=4096] @ (W[N][K] * scale[N/128][K/128])^T + bias[N]
#define M_DIM 4096
#define N_DIM 16384
#define K_DIM 4096

typedef __bf16 bf16x8 __attribute__((ext_vector_type(8)));
typedef float f32x4 __attribute__((ext_vector_type(4)));

__device__ __forceinline__ void gload16(const void* g, void* l) {
    __builtin_amdgcn_global_load_lds((__attribute__((address_space(1))) void*)g,
                                     (__attribute__((address_space(3))) void*)l, 16, 0, 0);
}

// ---------- prepass 1: x fp32 -> bf16 ----------
__global__ __launch_bounds__(256) void cvt_x_kernel(const float* __restrict__ x,
                                                    __hip_bfloat16* __restrict__ out,
                                                    int ngroups) {
    int i = blockIdx.x * blockDim.x + threadIdx.x;
    int stride = gridDim.x * blockDim.x;
    for (; i < ngroups; i += stride) {
        const float4* p = (const float4*)(x + (size_t)i * 8);
        float4 v0 = p[0];
        float4 v1 = p[1];
        bf16x8 r;
        r[0] = (__bf16)v0.x; r[1] = (__bf16)v0.y; r[2] = (__bf16)v0.z; r[3] = (__bf16)v0.w;
        r[4] = (__bf16)v1.x; r[5] = (__bf16)v1.y; r[6] = (__bf16)v1.z; r[7] = (__bf16)v1.w;
        *(bf16x8*)(out + (size_t)i * 8) = r;
    }
}

// ---------- prepass 2: W fp32 * blockscale -> bf16 ----------
__global__ __launch_bounds__(256) void dequant_w_kernel(const float* __restrict__ w,
                                                        const float* __restrict__ scale,
                                                        __hip_bfloat16* __restrict__ out) {
    const int ngroups = N_DIM * (K_DIM / 8);
    int i = blockIdx.x * blockDim.x + threadIdx.x;
    int stride = gridDim.x * blockDim.x;
    for (; i < ngroups; i += stride) {
        int row = i >> 9;            // K/8 = 512 groups per row
        int cg  = i & 511;
        float s = scale[(row >> 7) * (K_DIM / 128) + (cg >> 4)];
        const float4* p = (const float4*)(w + (size_t)i * 8);
        float4 v0 = p[0];
        float4 v1 = p[1];
        bf16x8 r;
        r[0] = (__bf16)(v0.x * s); r[1] = (__bf16)(v0.y * s);
        r[2] = (__bf16)(v0.z * s); r[3] = (__bf16)(v0.w * s);
        r[4] = (__bf16)(v1.x * s); r[5] = (__bf16)(v1.y * s);
        r[6] = (__bf16)(v1.z * s); r[7] = (__bf16)(v1.w * s);
        *(bf16x8*)(out + (size_t)i * 8) = r;
    }
}

// ---------- main GEMM: 256x256 tile, BK=64, 8 waves, 2-tile-deep pipeline ----------
// T1 XCD swizzle + T2 LDS XOR-swizzle (both-sides, rule #21) + T3/T4 counted
// vmcnt(8) across barriers (never 0 in loop) + T5 setprio around MFMA clusters.
// Pipeline invariants:
//   - prologue stages T0->buf0, T1->buf1 (8 gloads each, per thread 8+8)
//   - iter t head: vmcnt(8) allows only the newest 8 loads (tile t+1) to be
//     outstanding => tile t resident; s_barrier publishes across waves.
//   - all 24 ds_read_b128 of buf[cur] complete (lgkmcnt 0) BEFORE the release
//     barrier; stage of tile t+2 into buf[cur] is issued only after it.
//   - staged loads have one full iteration (~64 MFMAs/wave) to land.
__global__ __launch_bounds__(512, 2)
void gemm_bf16_kernel(const __hip_bfloat16* __restrict__ A,   // [M][K] bf16
                      const __hip_bfloat16* __restrict__ Bw,  // [N][K] bf16
                      const float* __restrict__ bias,
                      float* __restrict__ C) {                // [M][N] fp32
    constexpr int Mtiles = M_DIM / 256;            // 16
    constexpr int Ntiles = N_DIM / 256;            // 64
    constexpr int nwg = Mtiles * Ntiles;           // 1024 (div by 8)
    constexpr int NT = K_DIM / 64;                 // 64 K-tiles

    int bid = blockIdx.x;
    int swz = (bid & 7) * (nwg >> 3) + (bid >> 3);   // bijective XCD swizzle
    int bm = swz % Mtiles;
    int bn = swz / Mtiles;

    __shared__ __align__(16) __hip_bfloat16 sA[2][256 * 64];   // 64 KiB
    __shared__ __align__(16) __hip_bfloat16 sB[2][256 * 64];   // 64 KiB

    const int t = threadIdx.x;
    const int l = t & 63;
    const int w = t >> 6;        // wave 0..7
    const int wm = w >> 2;       // 0..1  (M half)
    const int wn = w & 3;        // 0..3  (N quarter)

    const int lr = l & 15;       // fragment row/col
    const int lk = l >> 4;       // k-group -> k offset lk*8
    const int rx = (lr & 7) << 3;          // read-side element-col XOR

    // staging: thread t, chunk j writes LDS row (j*64 + w*8 + (l>>3)), slot l&7.
    // pre-swizzled global element col keeps LDS dest linear (rule #21):
    const int srow = w * 8 + (l >> 3);
    const int scol = ((l & 7) ^ (l >> 3)) << 3;

    const size_t K = K_DIM;
    const __hip_bfloat16* aB = A  + (size_t)(bm * 256) * K;
    const __hip_bfloat16* bB = Bw + (size_t)(bn * 256) * K;

    f32x4 acc[8][4] = {};

#define STAGE(buf, kt)                                                          \
    do {                                                                        \
        const __hip_bfloat16* a0_ = aB + (kt) * 64 + scol;                      \
        const __hip_bfloat16* b0_ = bB + (kt) * 64 + scol;                      \
        char* la_ = (char*)&sA[(buf)][0] + w * 1024;                            \
        char* lb_ = (char*)&sB[(buf)][0] + w * 1024;                            \
        _Pragma("unroll")                                                       \
        for (int j = 0; j < 4; ++j) {                                           \
            gload16(a0_ + (size_t)(j * 64 + srow) * K, la_ + j * 8192);         \
            gload16(b0_ + (size_t)(j * 64 + srow) * K, lb_ + j * 8192);         \
        }                                                                       \
    } while (0)

    // prologue: two tiles in flight
    STAGE(0, 0);
    STAGE(1, 1);

    for (int kt = 0; kt < NT; ++kt) {
        const int cur = kt & 1;
        // ---- residency: allow only tile kt+1's 8 loads outstanding ----
        asm volatile("s_waitcnt vmcnt(8)" ::: "memory");
        __builtin_amdgcn_sched_barrier(0);
        __builtin_amdgcn_s_barrier();
        asm volatile("" ::: "memory");          // no reads hoisted above barrier
        __builtin_amdgcn_sched_barrier(0);

        const __hip_bfloat16* pa = &sA[cur][0];
        const __hip_bfloat16* pb = &sB[cur][0];

        bf16x8 a0[4], a1[4], a2[4], a3[4], b0[4], b1[4];
        const int c0 = (lk * 8) ^ rx;          // kk=0 swizzled col
        const int c1 = (32 + lk * 8) ^ rx;     // kk=1 swizzled col

        // ---- sub-phase reads run one step ahead of their MFMA cluster ----
        #pragma unroll
        for (int i = 0; i < 4; ++i) {
            a0[i] = *(const bf16x8*)(pa + (wm * 128 + i * 16 + lr) * 64 + c0);
            b0[i] = *(const bf16x8*)(pb + (wn * 64  + i * 16 + lr) * 64 + c0);
        }
        #pragma unroll
        for (int i = 0; i < 4; ++i)
            a1[i] = *(const bf16x8*)(pa + (wm * 128 + 64 + i * 16 + lr) * 64 + c0);
        __builtin_amdgcn_sched_barrier(0);

        __builtin_amdgcn_s_setprio(1);
        #pragma unroll
        for (int mi = 0; mi < 4; ++mi)
            #pragma unroll
            for (int ni = 0; ni < 4; ++ni)
                acc[mi][ni] = __builtin_amdgcn_mfma_f32_16x16x32_bf16(a0[mi], b0[ni], acc[mi][ni], 0, 0, 0);
        __builtin_amdgcn_s_setprio(0);

        #pragma unroll
        for (int i = 0; i < 4; ++i) {
            a2[i] = *(const bf16x8*)(pa + (wm * 128 + i * 16 + lr) * 64 + c1);
            b1[i] = *(const bf16x8*)(pb + (wn * 64  + i * 16 + lr) * 64 + c1);
        }
        __builtin_amdgcn_sched_barrier(0);

        __builtin_amdgcn_s_setprio(1);
        #pragma unroll
        for (int mi = 0; mi < 4; ++mi)
            #pragma unroll
            for (int ni = 0; ni < 4; ++ni)
                acc[4 + mi][ni] = __builtin_amdgcn_mfma_f32_16x16x32_bf16(a1[mi], b0[ni], acc[4 + mi][ni], 0, 0, 0);
        __builtin_amdgcn_s_setprio(0);

        #pragma unroll
        for (int i = 0; i < 4; ++i)
            a3[i] = *(const bf16x8*)(pa + (wm * 128 + 64 + i * 16 + lr) * 64 + c1);
        __builtin_amdgcn_sched_barrier(0);

        __builtin_amdgcn_s_setprio(1);
        #pragma unroll
        for (int mi = 0; mi < 4; ++mi)
            #pragma unroll
            for (int ni = 0; ni < 4; ++ni)
                acc[mi][ni] = __builtin_amdgcn_mfma_f32_16x16x32_bf16(a2[mi], b1[ni], acc[mi][ni], 0, 0, 0);
        __builtin_amdgcn_s_setprio(0);
        __builtin_amdgcn_sched_barrier(0);

        __builtin_amdgcn_s_setprio(1);
        #pragma unroll
        for (int mi = 0; mi < 4; ++mi)
            #pragma unroll
            for (int ni = 0; ni < 4; ++ni)
                acc[4 + mi][ni] = __builtin_amdgcn_mfma_f32_16x16x32_bf16(a3[mi], b1[ni], acc[4 + mi][ni], 0, 0, 0);
        __builtin_amdgcn_s_setprio(0);

        // ---- release buf[cur]: all ds_reads complete, then stage tile kt+2 ----
        __builtin_amdgcn_sched_barrier(0);
        asm volatile("s_waitcnt lgkmcnt(0)" ::: "memory");
        __builtin_amdgcn_sched_barrier(0);
        __builtin_amdgcn_s_barrier();
        asm volatile("" ::: "memory");
        __builtin_amdgcn_sched_barrier(0);
        if (kt + 2 < NT) {
            STAGE(cur, kt + 2);
        }
    }
#undef STAGE

    // epilogue: C/D layout col=lane&15, row=(lane>>4)*4+reg  [m89-verified]
    const int crow0 = bm * 256 + wm * 128;
    const int ccol0 = bn * 256 + wn * 64;
    #pragma unroll
    for (int ni = 0; ni < 4; ++ni) {
        int col = ccol0 + ni * 16 + lr;
        float bv = bias[col];
        #pragma unroll
        for (int mi = 0; mi < 8; ++mi) {
            int rbase = crow0 + mi * 16 + lk * 4;
            #pragma unroll
            for (int j = 0; j < 4; ++j) {
                C[(size_t)(rbase + j) * N_DIM + col] = acc[mi][ni][j] + bv;
            }
        }
    }
}

// ---------- fallback (ws too small): fp32 LDS-tiled, correct but slow ----------
__global__ __launch_bounds__(256)
void gemm_fallback(const float* __restrict__ X, const float* __restrict__ W,
                   const float* __restrict__ scale, const float* __restrict__ bias,
                   float* __restrict__ C) {
    int bm = blockIdx.x % (M_DIM / 64);
    int bn = blockIdx.x / (M_DIM / 64);
    __shared__ float sA[64][33];
    __shared__ float sB[64][33];
    int t = threadIdx.x;
    int tx = t & 15, ty = t >> 4;
    float acc[4][4] = {};
    for (int kt = 0; kt < K_DIM / 32; ++kt) {
        float s = scale[(bn >> 1) * (K_DIM / 128) + (kt >> 2)];
        #pragma unroll
        for (int i = 0; i < 8; ++i) {
            int idx = t + i * 256;
            int r = idx >> 5, c = idx & 31;
            sA[r][c] = X[(size_t)(bm * 64 + r) * K_DIM + kt * 32 + c];
            sB[r][c] = W[(size_t)(bn * 64 + r) * K_DIM + kt * 32 + c] * s;
        }
        __syncthreads();
        #pragma unroll
        for (int k = 0; k < 32; ++k) {
            float a[4], b[4];
            #pragma unroll
            for (int i = 0; i < 4; ++i) a[i] = sA[ty * 4 + i][k];
            #pragma unroll
            for (int j = 0; j < 4; ++j) b[j] = sB[tx * 4 + j][k];
            #pragma unroll
            for (int i = 0; i < 4; ++i)
                #pragma unroll
                for (int j = 0; j < 4; ++j) acc[i][j] += a[i] * b[j];
        }
        __syncthreads();
    }
    #pragma unroll
    for (int i = 0; i < 4; ++i)
        #pragma unroll
        for (int j = 0; j < 4; ++j) {
            int row = bm * 64 + ty * 4 + i;
            int col = bn * 64 + tx * 4 + j;
            C[(size_t)row * N_DIM + col] = acc[i][j] + bias[col];
        }
}

extern "C" void kernel_launch(void* const* d_in, const int* in_sizes, int n_in,
                              void* d_out, int out_size, void* d_ws, size_t ws_size,
                              hipStream_t stream) {
    const float* x     = (const float*)d_in[0];   // [2,2048,4096]
    const float* wgt   = (const float*)d_in[1];   // [16384,4096]
    const float* scale = (const float*)d_in[2];   // [128,32]
    const float* bias  = (const float*)d_in[3];   // [16384]
    float* out = (float*)d_out;                   // [2,2048,16384]

    const size_t need = ((size_t)M_DIM * K_DIM + (size_t)N_DIM * K_DIM) * sizeof(__hip_bfloat16);
    if (ws_size >= need) {
        __hip_bfloat16* xbf = (__hip_bfloat16*)d_ws;
        __hip_bfloat16* wbf = xbf + (size_t)M_DIM * K_DIM;
        cvt_x_kernel<<<2048, 256, 0, stream>>>(x, xbf, M_DIM * K_DIM / 8);
        dequant_w_kernel<<<4096, 256, 0, stream>>>(wgt, scale, wbf);
        gemm_bf16_kernel<<<(M_DIM / 256) * (N_DIM / 256), 512, 0, stream>>>(xbf, wbf, bias, out);
    } else {
        gemm_fallback<<<(M_DIM / 64) * (N_DIM / 64), 256, 0, stream>>>(x, wgt, scale, bias, out);
    }
}